// Round 6
// baseline (241.815 us; speedup 1.0000x reference)
//
#include <hip/hip_runtime.h>
#include <hip/hip_bf16.h>
#include <stdint.h>

// Problem constants
#define NROWS 8192
#define FDIM 256
#define MCOLS 20000
#define NT32 625           // 20000 / 32, exact -> no tail masking
#define MSPLIT 16
#define NCLS 1000
#define LOG2E 1.44269504088896f
#define LN2   0.69314718055994f

// ws layout (bytes), total ~15.5 MB:
//   Mb   bf16 memory          : [0, 10240000)
//   Fb   bf16 box*5*log2e     : [10240000, 14434304)
//   wsel weighted sel logits  : [14434304, 14467072)
//   pm   partial max [16][N]  : [14467072, 14991360)
//   ps   partial sum [16][N]  : [14991360, 15515648)
//   bpart block partials      : [15515648, 15515776)

typedef short short8 __attribute__((ext_vector_type(8)));
typedef float f32x4 __attribute__((ext_vector_type(4)));

typedef __attribute__((address_space(3))) unsigned int lds_u32;
typedef const __attribute__((address_space(1))) unsigned int glb_u32;

__device__ __forceinline__ float ex2(float x) {   // raw v_exp_f32 (2^x), no ocml wrapper
    float r;
    asm("v_exp_f32 %0, %1" : "=v"(r) : "v"(x));
    return r;
}

__device__ __forceinline__ unsigned short f2bf(float x) {
    unsigned u = __float_as_uint(x);
    unsigned r = (u + 0x7FFFu + ((u >> 16) & 1u)) >> 16;   // RNE
    return (unsigned short)r;
}

__global__ void conv_kernel(const float* __restrict__ in, unsigned short* __restrict__ out,
                            int n4, float scale) {
    int idx = blockIdx.x * blockDim.x + threadIdx.x;
    if (idx >= n4) return;
    float4 v = ((const float4*)in)[idx];
    ushort4 o;
    o.x = f2bf(v.x * scale); o.y = f2bf(v.y * scale);
    o.z = f2bf(v.z * scale); o.w = f2bf(v.w * scale);
    ((ushort4*)out)[idx] = o;
}

// Selected logits: wsel[i] = 5 * sum_d d * dot(F[i], Mem[trace[label_i][d]]), fp32-exact,
// natural-log domain (independent of the exp2 trick in lse_gemm).
__global__ void sel_kernel(const int* __restrict__ gt, const float* __restrict__ F,
                           const float* __restrict__ Mem, const int* __restrict__ trace,
                           float* __restrict__ wsel) {
    int lane = threadIdx.x & 63, wid = threadIdx.x >> 6;
    int i = blockIdx.x * 4 + wid;
    int label = gt[i];
    float w = 0.0f;
    if (label >= 0 && label < NCLS) {
        float4 fv = ((const float4*)(F + (size_t)i * FDIM))[lane];
        #pragma unroll
        for (int d = 1; d <= 3; ++d) {
            int tr = trace[label * 4 + d];
            float4 mv = ((const float4*)(Mem + (size_t)tr * FDIM))[lane];
            float dot = fv.x*mv.x + fv.y*mv.y + fv.z*mv.z + fv.w*mv.w;
            #pragma unroll
            for (int off = 32; off >= 1; off >>= 1) dot += __shfl_xor(dot, off, 64);
            w += (float)d * dot;
        }
    }
    if (lane == 0) wsel[i] = w * 5.0f;   // 1/T
}

// Fused GEMM + online log2-sum-exp2 partials.
// Block: 8 waves x 32 rows = 256 rows; rf=2 keeps per-wave regs ~116 (spill-proof).
// B tiles (32 cols x 256 k, 16 KiB) QUAD-buffered in LDS (64 KiB) via
// global_load_lds, prefetched 2 tiles ahead; end-of-tile wait is a counted
// s_waitcnt vmcnt(2) + raw s_barrier (never drains the fresh prefetch).
// 2 blocks/CU (launch_bounds(512,4): 128-reg budget) -> 4 waves/SIMD.
__global__ __launch_bounds__(512, 4) void lse_gemm(
        const unsigned short* __restrict__ Fb, const unsigned short* __restrict__ Mb,
        float* __restrict__ pm, float* __restrict__ ps) {
    __shared__ __align__(16) char smem[4 * 16384];  // 64 KiB, quad-buffer

    const int split  = blockIdx.x;   // 0..15 ; consecutive x -> different XCDs
    const int rowblk = blockIdx.y;   // 0..31
    const int tid  = threadIdx.x;
    const int lane = tid & 63, wid = tid >> 6;   // wid 0..7
    const int r0 = lane & 15, hi = lane >> 4;
    const int rowbase = rowblk * 256 + wid * 32;

    // A fragments: lane holds row (rowbase + rf*16 + r0), k = kk*32 + hi*8 .. +8
    short8 a[2][8];
    #pragma unroll
    for (int rf = 0; rf < 2; ++rf)
        #pragma unroll
        for (int kk = 0; kk < 8; ++kk)
            a[rf][kk] = *(const short8*)(Fb + (size_t)(rowbase + rf*16 + r0) * FDIM + kk*32 + hi*8);

    float m[8], s[8];
    #pragma unroll
    for (int q = 0; q < 8; ++q) { m[q] = -3.0e38f; s[q] = 0.0f; }

    const int t0 = (split * NT32) / MSPLIT;
    const int t1 = ((split + 1) * NT32) / MSPLIT;   // 39-40 tiles per split

    // Staging: tile = 1024 granules of 16B (32 rows x 512B); 512 threads x 2 calls.
    // LDS dest LINEAR (uniform base + lane*16); global source pre-swizzled
    // (slot o <- o ^ (row&7)) so the read-side XOR lands on linear data.
    int srcoff[2];
    #pragma unroll
    for (int c = 0; c < 2; ++c) {
        const int g = c * 512 + wid * 64 + lane;
        const int j = g >> 5, o = g & 31;
        srcoff[c] = j * 512 + ((o ^ (j & 7)) << 4);
    }

#define STAGE(BUF, t)                                                              \
    do {                                                                           \
        const char* srcT = (const char*)Mb + (size_t)(t) * 16384;                  \
        _Pragma("unroll")                                                          \
        for (int c = 0; c < 2; ++c) {                                              \
            __builtin_amdgcn_global_load_lds(                                      \
                (glb_u32*)(srcT + srcoff[c]),                                      \
                (lds_u32*)(smem + (BUF) * 16384 + c * 8192 + wid * 1024),          \
                16, 0, 0);                                                         \
        }                                                                          \
    } while (0)

    // Hoisted swizzled read offsets (per kk); buf/col-half fold into imm offsets.
    const int swzr = (r0 & 7) << 4;
    int roff[8];
    #pragma unroll
    for (int kk = 0; kk < 8; ++kk)
        roff[kk] = r0 * 512 + ((kk * 64 + hi * 16) ^ swzr);

#define COMPUTE(BASEPTR, t)                                                        \
    do {                                                                           \
        f32x4 c00 = {0,0,0,0}, c01 = {0,0,0,0}, c10 = {0,0,0,0}, c11 = {0,0,0,0};  \
        __builtin_amdgcn_s_setprio(1);                                             \
        _Pragma("unroll")                                                          \
        for (int kk = 0; kk < 8; ++kk) {                                           \
            const char* bp = (BASEPTR) + roff[kk];                                 \
            short8 b0 = *(const short8*)bp;                                        \
            short8 b1 = *(const short8*)(bp + 8192);                               \
            c00 = __builtin_amdgcn_mfma_f32_16x16x32_bf16(a[0][kk], b0, c00, 0, 0, 0); \
            c10 = __builtin_amdgcn_mfma_f32_16x16x32_bf16(a[1][kk], b0, c10, 0, 0, 0); \
            c01 = __builtin_amdgcn_mfma_f32_16x16x32_bf16(a[0][kk], b1, c01, 0, 0, 0); \
            c11 = __builtin_amdgcn_mfma_f32_16x16x32_bf16(a[1][kk], b1, c11, 0, 0, 0); \
        }                                                                          \
        __builtin_amdgcn_s_setprio(0);                                             \
        _Pragma("unroll")                                                          \
        for (int r = 0; r < 4; ++r) {                                              \
            { float v0 = c00[r], v1 = c01[r];                                      \
              float nm = fmaxf(fmaxf(m[r], v0), v1);                               \
              float em = ex2(m[r] - nm), e0 = ex2(v0 - nm), e1 = ex2(v1 - nm);     \
              s[r] = fmaf(s[r], em, e0 + e1); m[r] = nm; }                         \
            { float v0 = c10[r], v1 = c11[r];                                      \
              float nm = fmaxf(fmaxf(m[4 + r], v0), v1);                           \
              float em = ex2(m[4 + r] - nm), e0 = ex2(v0 - nm), e1 = ex2(v1 - nm); \
              s[4 + r] = fmaf(s[4 + r], em, e0 + e1); m[4 + r] = nm; }             \
        }                                                                          \
    } while (0)

    // One tile: prefetch t+2 into (BUF+2)&3, compute BUF, counted wait + barrier.
#define BODY(BUF, t)                                                               \
    do {                                                                           \
        const bool pref = (t) + 2 < t1;                                            \
        if (pref) STAGE(((BUF) + 2) & 3, (t) + 2);                                 \
        COMPUTE(smem + (BUF) * 16384, t);                                          \
        if (pref) { asm volatile("s_waitcnt vmcnt(2)" ::: "memory"); }             \
        else      { asm volatile("s_waitcnt vmcnt(0)" ::: "memory"); }             \
        __builtin_amdgcn_s_barrier();                                              \
        __builtin_amdgcn_sched_barrier(0);                                         \
    } while (0)

    // Prologue: fill 2 buffers, wait for the first, sync.
    STAGE(0, t0);
    STAGE(1, t0 + 1);
    asm volatile("s_waitcnt vmcnt(2)" ::: "memory");
    __builtin_amdgcn_s_barrier();
    __builtin_amdgcn_sched_barrier(0);

    int t = t0;
    while (t + 4 <= t1) {
        BODY(0, t); BODY(1, t + 1); BODY(2, t + 2); BODY(3, t + 3);
        t += 4;
    }
    while (t < t1) {   // remainder (<=3 tiles): runtime buffer base
        const int bufb = ((t - t0) & 3) * 16384;
        const bool pref = t + 2 < t1;
        if (pref) STAGE(((t - t0) + 2) & 3, t + 2);
        COMPUTE(smem + bufb, t);
        if (pref) { asm volatile("s_waitcnt vmcnt(2)" ::: "memory"); }
        else      { asm volatile("s_waitcnt vmcnt(0)" ::: "memory"); }
        __builtin_amdgcn_s_barrier();
        __builtin_amdgcn_sched_barrier(0);
        ++t;
    }

#undef BODY
#undef COMPUTE
#undef STAGE

    // combine the 16 lanes (r0 = column residue classes) of each hi-group
    #pragma unroll
    for (int off = 1; off <= 8; off <<= 1) {
        #pragma unroll
        for (int q = 0; q < 8; ++q) {
            float om = __shfl_xor(m[q], off, 64);
            float os = __shfl_xor(s[q], off, 64);
            float nm = fmaxf(m[q], om);
            float sn = fmaf(s[q], ex2(m[q] - nm), os * ex2(om - nm));
            m[q] = nm; s[q] = sn;
        }
    }
    if (r0 == 0) {
        #pragma unroll
        for (int rf = 0; rf < 2; ++rf)
            #pragma unroll
            for (int r = 0; r < 4; ++r) {
                int row = rowbase + rf * 16 + hi * 4 + r;   // C/D: row=(lane>>4)*4+reg
                pm[split * NROWS + row] = m[rf * 4 + r];
                ps[split * NROWS + row] = s[rf * 4 + r];
            }
    }
}

__global__ void finalize_kernel(const int* __restrict__ gt, const float* __restrict__ wsel,
                                const float* __restrict__ pm, const float* __restrict__ ps,
                                float* __restrict__ bpart) {
    int tid = threadIdx.x;
    int i = blockIdx.x * 256 + tid;
    float mv[MSPLIT];
    float M = -3.0e38f;
    #pragma unroll
    for (int k = 0; k < MSPLIT; ++k) { mv[k] = pm[k * NROWS + i]; M = fmaxf(M, mv[k]); }
    float S = 0.0f;
    #pragma unroll
    for (int k = 0; k < MSPLIT; ++k) S += ps[k * NROWS + i] * ex2(mv[k] - M);
    float lse = (M + __log2f(S)) * LN2;   // back to natural-log domain
    int label = gt[i];
    float per = (label >= 0 && label < NCLS) ? (lse - wsel[i] * (1.0f / 6.0f)) : 0.0f;
    #pragma unroll
    for (int off = 32; off >= 1; off >>= 1) per += __shfl_xor(per, off, 64);
    __shared__ float red[4];
    int lane = tid & 63, wid = tid >> 6;
    if (lane == 0) red[wid] = per;
    __syncthreads();
    if (tid == 0) bpart[blockIdx.x] = red[0] + red[1] + red[2] + red[3];
}

__global__ void sum_kernel(const float* __restrict__ bpart, float* __restrict__ out) {
    int tid = threadIdx.x;
    float v = (tid < 32) ? bpart[tid] : 0.0f;
    #pragma unroll
    for (int off = 32; off >= 1; off >>= 1) v += __shfl_xor(v, off, 64);
    if (tid == 0) out[0] = 0.001f * v;
}

extern "C" void kernel_launch(void* const* d_in, const int* in_sizes, int n_in,
                              void* d_out, int out_size, void* d_ws, size_t ws_size,
                              hipStream_t stream) {
    const int*   gt    = (const int*)d_in[0];
    const float* F     = (const float*)d_in[1];
    const float* Mem   = (const float*)d_in[2];
    const int*   trace = (const int*)d_in[3];
    float* out = (float*)d_out;

    char* w = (char*)d_ws;
    unsigned short* Mb = (unsigned short*)w;
    unsigned short* Fb = (unsigned short*)(w + 10240000);
    float* wsel  = (float*)(w + 14434304);
    float* pm    = (float*)(w + 14467072);
    float* ps    = (float*)(w + 14991360);
    float* bpart = (float*)(w + 15515648);

    conv_kernel<<<dim3((MCOLS * FDIM / 4) / 256), dim3(256), 0, stream>>>(Mem, Mb, MCOLS * FDIM / 4, 1.0f);
    conv_kernel<<<dim3((NROWS * FDIM / 4) / 256), dim3(256), 0, stream>>>(F, Fb, NROWS * FDIM / 4, 5.0f * LOG2E);
    sel_kernel<<<dim3(NROWS / 4), dim3(256), 0, stream>>>(gt, F, Mem, trace, wsel);
    lse_gemm<<<dim3(MSPLIT, NROWS / 256), dim3(512), 0, stream>>>(Fb, Mb, pm, ps);
    finalize_kernel<<<dim3(NROWS / 256), dim3(256), 0, stream>>>(gt, wsel, pm, ps, bpart);
    sum_kernel<<<dim3(1), dim3(64), 0, stream>>>(bpart, out);
}

// Round 7
// 111.874 us; speedup vs baseline: 2.1615x; 2.1615x over previous
//
#include <hip/hip_runtime.h>
#include <hip/hip_bf16.h>
#include <stdint.h>

// Problem constants
#define NROWS 8192
#define FDIM 256
#define MCOLS 20000
#define NT32 625           // 20000 / 32, exact -> no tail masking
#define MSPLIT 16
#define NCLS 1000
#define LOG2E 1.44269504088896f
#define LN2   0.69314718055994f

// ws layout (bytes), total ~15.5 MB:
//   Mb   bf16 memory          : [0, 10240000)
//   Fb   bf16 box*5*log2e     : [10240000, 14434304)
//   wsel weighted sel logits  : [14434304, 14467072)
//   pm   partial max [16][N]  : [14467072, 14991360)
//   ps   partial sum [16][N]  : [14991360, 15515648)
//   bpart block partials      : [15515648, 15515776)

typedef short short8 __attribute__((ext_vector_type(8)));
typedef float f32x4 __attribute__((ext_vector_type(4)));

typedef __attribute__((address_space(3))) unsigned int lds_u32;
typedef const __attribute__((address_space(1))) unsigned int glb_u32;

__device__ __forceinline__ float ex2(float x) {   // raw v_exp_f32 (2^x), no ocml wrapper
    float r;
    asm("v_exp_f32 %0, %1" : "=v"(r) : "v"(x));
    return r;
}

__device__ __forceinline__ unsigned short f2bf(float x) {
    unsigned u = __float_as_uint(x);
    unsigned r = (u + 0x7FFFu + ((u >> 16) & 1u)) >> 16;   // RNE
    return (unsigned short)r;
}

__global__ void conv_kernel(const float* __restrict__ in, unsigned short* __restrict__ out,
                            int n4, float scale) {
    int idx = blockIdx.x * blockDim.x + threadIdx.x;
    if (idx >= n4) return;
    float4 v = ((const float4*)in)[idx];
    ushort4 o;
    o.x = f2bf(v.x * scale); o.y = f2bf(v.y * scale);
    o.z = f2bf(v.z * scale); o.w = f2bf(v.w * scale);
    ((ushort4*)out)[idx] = o;
}

// Selected logits: wsel[i] = 5 * sum_d d * dot(F[i], Mem[trace[label_i][d]]), fp32-exact,
// natural-log domain (independent of the exp2 trick in lse_gemm).
__global__ void sel_kernel(const int* __restrict__ gt, const float* __restrict__ F,
                           const float* __restrict__ Mem, const int* __restrict__ trace,
                           float* __restrict__ wsel) {
    int lane = threadIdx.x & 63, wid = threadIdx.x >> 6;
    int i = blockIdx.x * 4 + wid;
    int label = gt[i];
    float w = 0.0f;
    if (label >= 0 && label < NCLS) {
        float4 fv = ((const float4*)(F + (size_t)i * FDIM))[lane];
        #pragma unroll
        for (int d = 1; d <= 3; ++d) {
            int tr = trace[label * 4 + d];
            float4 mv = ((const float4*)(Mem + (size_t)tr * FDIM))[lane];
            float dot = fv.x*mv.x + fv.y*mv.y + fv.z*mv.z + fv.w*mv.w;
            #pragma unroll
            for (int off = 32; off >= 1; off >>= 1) dot += __shfl_xor(dot, off, 64);
            w += (float)d * dot;
        }
    }
    if (lane == 0) wsel[i] = w * 5.0f;   // 1/T
}

// Fused GEMM + online log2-sum-exp2 partials.
// EXACT R3 register/block shape (256 thr, launch_bounds(256,2), rf=2, VGPR~84,
// proven spill-free). Only the sync structure changes: TRIPLE-buffered LDS
// (48 KiB), prefetch distance 2, counted s_waitcnt vmcnt(4) + raw s_barrier
// per tile (the fresh prefetch stays in flight across the barrier).
// 48 KiB/block -> 3 blocks/CU = 3 waves/SIMD.
__global__ __launch_bounds__(256, 2) void lse_gemm(
        const unsigned short* __restrict__ Fb, const unsigned short* __restrict__ Mb,
        float* __restrict__ pm, float* __restrict__ ps) {
    __shared__ __align__(16) char smem[3 * 16384];  // 48 KiB, triple-buffer

    const int split  = blockIdx.x;   // 0..15 ; consecutive x -> different XCDs
    const int rowblk = blockIdx.y;   // 0..63
    const int tid  = threadIdx.x;
    const int lane = tid & 63, wid = tid >> 6;
    const int r0 = lane & 15, hi = lane >> 4;
    const int rowbase = rowblk * 128 + wid * 32;

    // A fragments: lane holds row (rowbase + rf*16 + r0), k = kk*32 + hi*8 .. +8
    short8 a[2][8];
    #pragma unroll
    for (int rf = 0; rf < 2; ++rf)
        #pragma unroll
        for (int kk = 0; kk < 8; ++kk)
            a[rf][kk] = *(const short8*)(Fb + (size_t)(rowbase + rf*16 + r0) * FDIM + kk*32 + hi*8);

    float m[8], s[8];
    #pragma unroll
    for (int q = 0; q < 8; ++q) { m[q] = -3.0e38f; s[q] = 0.0f; }

    const int t0 = (split * NT32) / MSPLIT;
    const int t1 = ((split + 1) * NT32) / MSPLIT;   // 39-40 tiles per split

    // Staging: tile = 1024 granules of 16B (32 rows x 512B); 256 threads x 4 calls.
    // LDS dest LINEAR; global source pre-swizzled (o ^ (j&7)) so the read-side
    // XOR hits linear data.
    int srcoff[4];
    #pragma unroll
    for (int c = 0; c < 4; ++c) {
        const int g = (wid * 4 + c) * 64 + lane;
        const int j = g >> 5, o = g & 31;
        srcoff[c] = j * 512 + ((o ^ (j & 7)) << 4);
    }

#define STAGE(BUF, t)                                                              \
    do {                                                                           \
        const char* srcT = (const char*)Mb + (size_t)(t) * 16384;                  \
        _Pragma("unroll")                                                          \
        for (int c = 0; c < 4; ++c) {                                              \
            __builtin_amdgcn_global_load_lds(                                      \
                (glb_u32*)(srcT + srcoff[c]),                                      \
                (lds_u32*)(smem + (BUF) * 16384 + (wid * 4 + c) * 1024),           \
                16, 0, 0);                                                         \
        }                                                                          \
    } while (0)

    // Hoisted swizzled read offsets (per kk); buf/col-half fold into imm offsets.
    const int swzr = (r0 & 7) << 4;
    int roff[8];
    #pragma unroll
    for (int kk = 0; kk < 8; ++kk)
        roff[kk] = r0 * 512 + ((kk * 64 + hi * 16) ^ swzr);

#define COMPUTE(BASEPTR)                                                           \
    do {                                                                           \
        f32x4 c00 = {0,0,0,0}, c01 = {0,0,0,0}, c10 = {0,0,0,0}, c11 = {0,0,0,0};  \
        __builtin_amdgcn_s_setprio(1);                                             \
        _Pragma("unroll")                                                          \
        for (int kk = 0; kk < 8; ++kk) {                                           \
            const char* bp = (BASEPTR) + roff[kk];                                 \
            short8 b0 = *(const short8*)bp;                                        \
            short8 b1 = *(const short8*)(bp + 8192);                               \
            c00 = __builtin_amdgcn_mfma_f32_16x16x32_bf16(a[0][kk], b0, c00, 0, 0, 0); \
            c10 = __builtin_amdgcn_mfma_f32_16x16x32_bf16(a[1][kk], b0, c10, 0, 0, 0); \
            c01 = __builtin_amdgcn_mfma_f32_16x16x32_bf16(a[0][kk], b1, c01, 0, 0, 0); \
            c11 = __builtin_amdgcn_mfma_f32_16x16x32_bf16(a[1][kk], b1, c11, 0, 0, 0); \
        }                                                                          \
        __builtin_amdgcn_s_setprio(0);                                             \
        _Pragma("unroll")                                                          \
        for (int r = 0; r < 4; ++r) {                                              \
            { float v0 = c00[r], v1 = c01[r];                                      \
              float nm = fmaxf(fmaxf(m[r], v0), v1);                               \
              float em = ex2(m[r] - nm), e0 = ex2(v0 - nm), e1 = ex2(v1 - nm);     \
              s[r] = fmaf(s[r], em, e0 + e1); m[r] = nm; }                         \
            { float v0 = c10[r], v1 = c11[r];                                      \
              float nm = fmaxf(fmaxf(m[4 + r], v0), v1);                           \
              float em = ex2(m[4 + r] - nm), e0 = ex2(v0 - nm), e1 = ex2(v1 - nm); \
              s[4 + r] = fmaf(s[4 + r], em, e0 + e1); m[4 + r] = nm; }             \
        }                                                                          \
    } while (0)

    // One tile: prefetch t+2 into buf (BUF+2)%3 (== buf of t-1, all readers past
    // the previous barrier -> WAR-safe), compute BUF, then wait ONLY the older
    // STAGE's 4 loads (vmcnt(4)) and barrier. Fresh prefetch stays in flight.
#define BODY(BUF, t)                                                               \
    do {                                                                           \
        const bool pref = (t) + 2 < t1;                                            \
        if (pref) STAGE(((BUF) + 2) % 3, (t) + 2);                                 \
        COMPUTE(smem + (BUF) * 16384);                                             \
        if (pref) { asm volatile("s_waitcnt vmcnt(4)" ::: "memory"); }             \
        else      { asm volatile("s_waitcnt vmcnt(0)" ::: "memory"); }             \
        __builtin_amdgcn_s_barrier();                                              \
        __builtin_amdgcn_sched_barrier(0);                                         \
    } while (0)

    // Prologue: fill 2 buffers, wait for the first (4 newest may stay in flight).
    STAGE(0, t0);
    STAGE(1, t0 + 1);
    asm volatile("s_waitcnt vmcnt(4)" ::: "memory");
    __builtin_amdgcn_s_barrier();
    __builtin_amdgcn_sched_barrier(0);

    int t = t0;
    while (t + 3 <= t1) {
        BODY(0, t); BODY(1, t + 1); BODY(2, t + 2);
        t += 3;
    }
    while (t < t1) {   // remainder (<=2 tiles): runtime buffer base
        const int bufb = ((t - t0) % 3) * 16384;
        const bool pref = t + 2 < t1;
        if (pref) STAGE((t - t0 + 2) % 3, t + 2);
        COMPUTE(smem + bufb);
        if (pref) { asm volatile("s_waitcnt vmcnt(4)" ::: "memory"); }
        else      { asm volatile("s_waitcnt vmcnt(0)" ::: "memory"); }
        __builtin_amdgcn_s_barrier();
        __builtin_amdgcn_sched_barrier(0);
        ++t;
    }

#undef BODY
#undef COMPUTE
#undef STAGE

    // combine the 16 lanes (r0 = column residue classes) of each hi-group
    #pragma unroll
    for (int off = 1; off <= 8; off <<= 1) {
        #pragma unroll
        for (int q = 0; q < 8; ++q) {
            float om = __shfl_xor(m[q], off, 64);
            float os = __shfl_xor(s[q], off, 64);
            float nm = fmaxf(m[q], om);
            float sn = fmaf(s[q], ex2(m[q] - nm), os * ex2(om - nm));
            m[q] = nm; s[q] = sn;
        }
    }
    if (r0 == 0) {
        #pragma unroll
        for (int rf = 0; rf < 2; ++rf)
            #pragma unroll
            for (int r = 0; r < 4; ++r) {
                int row = rowbase + rf * 16 + hi * 4 + r;   // C/D: row=(lane>>4)*4+reg
                pm[split * NROWS + row] = m[rf * 4 + r];
                ps[split * NROWS + row] = s[rf * 4 + r];
            }
    }
}

__global__ void finalize_kernel(const int* __restrict__ gt, const float* __restrict__ wsel,
                                const float* __restrict__ pm, const float* __restrict__ ps,
                                float* __restrict__ bpart) {
    int tid = threadIdx.x;
    int i = blockIdx.x * 256 + tid;
    float mv[MSPLIT];
    float M = -3.0e38f;
    #pragma unroll
    for (int k = 0; k < MSPLIT; ++k) { mv[k] = pm[k * NROWS + i]; M = fmaxf(M, mv[k]); }
    float S = 0.0f;
    #pragma unroll
    for (int k = 0; k < MSPLIT; ++k) S += ps[k * NROWS + i] * ex2(mv[k] - M);
    float lse = (M + __log2f(S)) * LN2;   // back to natural-log domain
    int label = gt[i];
    float per = (label >= 0 && label < NCLS) ? (lse - wsel[i] * (1.0f / 6.0f)) : 0.0f;
    #pragma unroll
    for (int off = 32; off >= 1; off >>= 1) per += __shfl_xor(per, off, 64);
    __shared__ float red[4];
    int lane = tid & 63, wid = tid >> 6;
    if (lane == 0) red[wid] = per;
    __syncthreads();
    if (tid == 0) bpart[blockIdx.x] = red[0] + red[1] + red[2] + red[3];
}

__global__ void sum_kernel(const float* __restrict__ bpart, float* __restrict__ out) {
    int tid = threadIdx.x;
    float v = (tid < 32) ? bpart[tid] : 0.0f;
    #pragma unroll
    for (int off = 32; off >= 1; off >>= 1) v += __shfl_xor(v, off, 64);
    if (tid == 0) out[0] = 0.001f * v;
}

extern "C" void kernel_launch(void* const* d_in, const int* in_sizes, int n_in,
                              void* d_out, int out_size, void* d_ws, size_t ws_size,
                              hipStream_t stream) {
    const int*   gt    = (const int*)d_in[0];
    const float* F     = (const float*)d_in[1];
    const float* Mem   = (const float*)d_in[2];
    const int*   trace = (const int*)d_in[3];
    float* out = (float*)d_out;

    char* w = (char*)d_ws;
    unsigned short* Mb = (unsigned short*)w;
    unsigned short* Fb = (unsigned short*)(w + 10240000);
    float* wsel  = (float*)(w + 14434304);
    float* pm    = (float*)(w + 14467072);
    float* ps    = (float*)(w + 14991360);
    float* bpart = (float*)(w + 15515648);

    conv_kernel<<<dim3((MCOLS * FDIM / 4) / 256), dim3(256), 0, stream>>>(Mem, Mb, MCOLS * FDIM / 4, 1.0f);
    conv_kernel<<<dim3((NROWS * FDIM / 4) / 256), dim3(256), 0, stream>>>(F, Fb, NROWS * FDIM / 4, 5.0f * LOG2E);
    sel_kernel<<<dim3(NROWS / 4), dim3(256), 0, stream>>>(gt, F, Mem, trace, wsel);
    lse_gemm<<<dim3(MSPLIT, NROWS / 128), dim3(256), 0, stream>>>(Fb, Mb, pm, ps);
    finalize_kernel<<<dim3(NROWS / 256), dim3(256), 0, stream>>>(gt, wsel, pm, ps, bpart);
    sum_kernel<<<dim3(1), dim3(64), 0, stream>>>(bpart, out);
}